// Round 9
// baseline (2368.625 us; speedup 1.0000x reference)
//
#include <hip/hip_runtime.h>
#include <hip/hip_bf16.h>

using short8   = __attribute__((ext_vector_type(8))) short;
using floatx4  = __attribute__((ext_vector_type(4))) float;
using floatx16 = __attribute__((ext_vector_type(16))) float;
typedef unsigned short u16;
typedef unsigned int   u32;

#define DEVINL static __device__ __forceinline__

constexpr int kB = 512;    // batch
constexpr int kH = 1024;   // hidden
constexpr int kO = 256;    // output dim
constexpr int kT = 128;    // timesteps
constexpr int kG = 4096;   // 4*H gate columns

DEVINL u16 f2bf(float x) {
  union { float f; unsigned u; } v; v.f = x;
  unsigned r = v.u + 0x7fffu + ((v.u >> 16) & 1u);   // RNE
  return (u16)(r >> 16);
}
DEVINL float sigm(float x)  { return 1.0f / (1.0f + __expf(-x)); }
DEVINL float tanhx(float x) { return 1.0f - 2.0f / (__expf(2.0f * x) + 1.0f); }

DEVINL void gload16(const void* src, void* ldsbase) {
  __builtin_amdgcn_global_load_lds((__attribute__((address_space(1))) void*)(char*)src,
                                   (__attribute__((address_space(3))) void*)ldsbase,
                                   16, 0, 0);
}
DEVINL short8 lds8(const void* p) { return *(const short8*)p; }

// ---------------- prep kernels ----------------

__global__ void k_init(const float* __restrict__ enc, float* __restrict__ c,
                       u16* __restrict__ h0) {
  int i = blockIdx.x * 256 + threadIdx.x;
  c[i]  = 0.0f;
  h0[i] = f2bf(enc[i]);
}

// zero the 256 per-block arrival slots (128B stride -> 8192 u32 = 32 KB)
__global__ void k_zbar(u32* __restrict__ bar) {
  bar[blockIdx.x * 256 + threadIdx.x] = 0u;
}

// bias0 = b_ih + b_hh ; bias1 = bias0 + W_ih @ b_out
__global__ void k_bias(const float* __restrict__ bih, const float* __restrict__ bhh,
                       const float* __restrict__ Wih, const float* __restrict__ bout,
                       float* __restrict__ bias0, float* __restrict__ bias1) {
  int n = blockIdx.x * 256 + threadIdx.x;        // 0..4095
  float b0 = bih[n] + bhh[n];
  const float* row = Wih + (long)n * 256;
  float s = 0.f;
  for (int j = 0; j < 256; ++j) s += row[j] * bout[j];
  bias0[n] = b0;
  bias1[n] = b0 + s;
}

// Wt0[r(n,g)][k] = bf16(W_hh[g*1024+n][k]);  r(n,g) = (n>>4)*64 + g*16 + (n&15)
__global__ void k_w0(const float* __restrict__ Whh, u16* __restrict__ Wt0) {
  const int r = blockIdx.x;                       // 4096 rows
  const int k = threadIdx.x * 4;
  const int n = ((r >> 6) << 4) | (r & 15);
  const int g = (r >> 4) & 3;
  const float4 v = *(const float4*)(Whh + (long)(g * 1024 + n) * 1024 + k);
  ushort4 o; o.x = f2bf(v.x); o.y = f2bf(v.y); o.z = f2bf(v.z); o.w = f2bf(v.w);
  *(ushort4*)(Wt0 + (long)r * 1024 + k) = o;
}

// Wob = bf16(W_out)
__global__ void k_wo(const float* __restrict__ Wout, u16* __restrict__ Wob) {
  const long i = ((long)blockIdx.x * 256 + threadIdx.x) * 4;
  const float4 v = *(const float4*)(Wout + i);
  ushort4 o; o.x = f2bf(v.x); o.y = f2bf(v.y); o.z = f2bf(v.z); o.w = f2bf(v.w);
  *(ushort4*)(Wob + i) = o;
}

// Wt1[r(n,g)][k] = bf16( W_hh[g*1024+n][k] + sum_j W_out[j][k]*W_ih[g*1024+n][j] )
__global__ __launch_bounds__(256) void k_w1(
    const float* __restrict__ Wih, const float* __restrict__ Wout,
    const float* __restrict__ Whh, u16* __restrict__ Wt1) {
  __shared__ float sW[16][256];
  const int g = blockIdx.x & 3, n16 = blockIdx.x >> 2;
  const int tid = threadIdx.x;
#pragma unroll
  for (int nl = 0; nl < 16; ++nl)
    sW[nl][tid] = Wih[(long)(g * 1024 + n16 * 16 + nl) * 256 + tid];
  __syncthreads();
  const int k4 = tid * 4;
  float acc[16][4];
#pragma unroll
  for (int nl = 0; nl < 16; ++nl)
#pragma unroll
    for (int q = 0; q < 4; ++q) acc[nl][q] = 0.f;
  for (int j = 0; j < 256; ++j) {
    const float4 wo = *(const float4*)(Wout + (long)j * 1024 + k4);
#pragma unroll
    for (int nl = 0; nl < 16; ++nl) {
      const float w = sW[nl][j];
      acc[nl][0] += w * wo.x; acc[nl][1] += w * wo.y;
      acc[nl][2] += w * wo.z; acc[nl][3] += w * wo.w;
    }
  }
#pragma unroll
  for (int nl = 0; nl < 16; ++nl) {
    const int n = n16 * 16 + nl;
    const int rout = n16 * 64 + g * 16 + nl;
    const float* hh = Whh + (long)(g * 1024 + n) * 1024 + k4;
    ushort4 o;
    o.x = f2bf(hh[0] + acc[nl][0]); o.y = f2bf(hh[1] + acc[nl][1]);
    o.z = f2bf(hh[2] + acc[nl][2]); o.w = f2bf(hh[3] + acc[nl][3]);
    *(ushort4*)(Wt1 + (long)rout * 1024 + k4) = o;
  }
}

// ---------------- step 0 (old-style, Wt0/bias0) ----------------
__global__ __launch_bounds__(256) void k_step(
    const u16* __restrict__ Xprev, u16* __restrict__ Hnext,
    float* __restrict__ c, const u16* __restrict__ Wt,
    const float* __restrict__ bias) {
  __shared__ u16 As[64 * 64];
  __shared__ u16 Bs[128 * 64];

  const int tid  = threadIdx.x;
  const int lane = tid & 63;
  const int wid  = tid >> 6;
  const int wr   = wid >> 1;
  const int wc   = wid & 1;
  const int n0   = blockIdx.x * 32;
  const int m0   = blockIdx.y * 64;
  const long wrow0 = (long)n0 * 4;
  const int hi  = lane >> 4;
  const int l15 = lane & 15;

  floatx4 acc[2][4];
#pragma unroll
  for (int a2 = 0; a2 < 2; ++a2)
#pragma unroll
    for (int f = 0; f < 4; ++f)
#pragma unroll
      for (int r = 0; r < 4; ++r) acc[a2][f][r] = 0.0f;

  for (int kt = 0; kt < 16; ++kt) {
    const int kb = kt * 128;
#pragma unroll
    for (int i = 0; i < 2; ++i) {
      const int u = i * 256 + tid;
      const int row = u >> 3;
      const int off = (u & 7) * 16;
      const char* src = (const char*)Xprev + ((long)(m0 + row) << 11) + kb +
                        (off ^ ((row & 7) << 4));
      gload16(src, (char*)As + (i * 256 + wid * 64) * 16);
    }
#pragma unroll
    for (int i = 0; i < 4; ++i) {
      const int u = i * 256 + tid;
      const int col = u >> 3;
      const int off = (u & 7) * 16;
      const char* src = (const char*)Wt + ((wrow0 + col) << 11) + kb +
                        (off ^ ((col & 7) << 4));
      gload16(src, (char*)Bs + (i * 256 + wid * 64) * 16);
    }
    __syncthreads();
#pragma unroll
    for (int ks = 0; ks < 2; ++ks) {
      const int kbyte = ks * 64 + hi * 16;
      const int ra = wr * 32 + l15;
      short8 a0 = lds8((const char*)As + ra * 128 + (kbyte ^ ((ra & 7) << 4)));
      const int rb = ra + 16;
      short8 a1 = lds8((const char*)As + rb * 128 + (kbyte ^ ((rb & 7) << 4)));
#pragma unroll
      for (int f = 0; f < 4; ++f) {
        const int colx = wc * 64 + f * 16 + l15;
        short8 b = lds8((const char*)Bs + colx * 128 + (kbyte ^ ((colx & 7) << 4)));
        acc[0][f] = __builtin_amdgcn_mfma_f32_16x16x32_bf16(a0, b, acc[0][f], 0, 0, 0);
        acc[1][f] = __builtin_amdgcn_mfma_f32_16x16x32_bf16(a1, b, acc[1][f], 0, 0, 0);
      }
    }
    __syncthreads();
  }

  const int n_glob = n0 + wc * 16 + l15;
  const float bi = bias[n_glob];
  const float bf = bias[1024 + n_glob];
  const float bg = bias[2048 + n_glob];
  const float bo = bias[3072 + n_glob];
#pragma unroll
  for (int a2 = 0; a2 < 2; ++a2) {
#pragma unroll
    for (int r = 0; r < 4; ++r) {
      const int row = m0 + wr * 32 + a2 * 16 + hi * 4 + r;
      const long ci = (long)row * kH + n_glob;
      const float iv = sigm(acc[a2][0][r] + bi);
      const float fv = sigm(acc[a2][1][r] + bf);
      const float gv = tanhx(acc[a2][2][r] + bg);
      const float ov = sigm(acc[a2][3][r] + bo);
      const float cn = fv * c[ci] + iv * gv;
      c[ci] = cn;
      Hnext[ci] = f2bf(ov * tanhx(cn));
    }
  }
}

// ---------------- persistent recurrence: steps 1..127 ----------------
// 256 blocks (1/CU, 144KB LDS), 8 waves. Block (bg,hg) owns batch rows
// bg*128.. and Wt1 rows hg*64.. (16 hidden x 4 gates).
// Core: mfma_f32_32x32x16_bf16 — wave (rt,ct) owns a 32x32 output tile
// (rt=w>>1 row-tile, ct=w&1 col-tile). B LDS layout is linear in lane:
// addr = ct*65536 + j*1024 + l*16 (16-bit imm offsets, conflict-free),
// HALVING per-step ds_read_b128 count vs the 16x16x32 core (512 vs 1024).
// Gates land split across ct-waves -> 16KB LDS gate-bounce E[row64][hid][gate]
// in two 64-row phases. c in registers. h handoff: relaxed agent stores;
// barrier: per-block arrival slots + wave-0 parallel polling (round 8).
__global__ __launch_bounds__(512, 2) void k_persist(
    const u16* __restrict__ Wt,      // Wt1 [4096][1024]
    const float* __restrict__ bias,  // bias1
    const float* __restrict__ cin,   // c after step 0
    u16* __restrict__ Hbuf,          // 129 slices of [512][1024]
    u32* __restrict__ bar) {         // 256 slots, 128B stride
  __shared__ u16  Wlds[64 * 1024];   // 128 KB weights
  __shared__ float E[64 * 16 * 4];   // 16 KB gate bounce

  const int tid = threadIdx.x;
  const int l   = tid & 63;
  const int w   = tid >> 6;          // wave 0..7
  const int rt  = w >> 1;            // row-tile 0..3 (32 batch rows each)
  const int ct  = w & 1;             // col-tile 0..1 (32 Wt rows each)
  const int col = l & 31;
  const int hi  = l >> 5;            // k-half 0..1
  const int xcd  = blockIdx.x & 7;
  const int slot = blockIdx.x >> 3;            // 0..31
  const int bg   = xcd >> 1;                   // 0..3
  const int hg   = (xcd & 1) * 32 + slot;      // 0..63
  const int m0   = bg * 128;
  const int myblk = blockIdx.x;
  const int pblk = ((l & 31) * 8) + (bg * 2) + (l >> 5);

  // stage weights in exact 32x32x16 read order:
  // LDS byte addr = ct*65536 + j*1024 + hi*512 + col*16  holds
  // Wt[hg*64 + ct*32 + col][bytes j*32 + hi*16 .. +16]
  {
    const long wrow0 = (long)hg * 64;
#pragma unroll
    for (int rr = 0; rr < 16; ++rr) {
      const int u   = rr * 512 + tid;          // 16B chunk id 0..8191
      const int ctu = u >> 12;
      const int ju  = (u >> 6) & 63;
      const int hiu = (u >> 5) & 1;
      const int cu  = u & 31;
      const char* src = (const char*)Wt + ((wrow0 + ctu * 32 + cu) << 11) +
                        (ju << 5) + (hiu << 4);
      gload16(src, (char*)Wlds + (long)u * 16);
    }
  }

  // epilogue thread mapping: thread owns (hid, row-pair) x 2 halves
  const int hid = tid & 15;
  const int rp  = tid >> 4;                    // 0..31
  const int ncol = hg * 16 + hid;
  const float bi  = bias[ncol];
  const float bf_ = bias[1024 + ncol];
  const float bg_ = bias[2048 + ncol];
  const float bo  = bias[3072 + ncol];
  float creg[4];
#pragma unroll
  for (int hp = 0; hp < 2; ++hp)
#pragma unroll
    for (int p = 0; p < 2; ++p)
      creg[hp * 2 + p] = cin[(long)(m0 + hp * 64 + rp * 2 + p) * kH + ncol];

  __syncthreads();                             // weights staged (vmcnt drained)

  const char* Bb = (const char*)Wlds + ct * 65536 + l * 16;
  const long HSB   = (long)kB * kH * 2;
  const long abase = (long)(m0 + rt * 32 + col) * 2048 + hi * 16;

  for (int t = 1; t < kT; ++t) {
    const char* Asrc = (const char*)Hbuf + (long)t * HSB + abase;
    floatx16 accE, accO;
#pragma unroll
    for (int r = 0; r < 16; ++r) { accE[r] = 0.f; accO[r] = 0.f; }

    // 2-deep rolling A banks (8 j-frags each, 16 loads in flight)
    short8 bank[2][8];
#pragma unroll
    for (int b = 0; b < 2; ++b)
#pragma unroll
      for (int q = 0; q < 8; ++q)
        bank[b][q] = *(const short8*)(Asrc + ((b * 8 + q) << 5));

#pragma unroll
    for (int jb = 0; jb < 8; ++jb) {
#pragma unroll
      for (int q = 0; q < 8; ++q) {
        const int j = jb * 8 + q;
        short8 bfrag = lds8(Bb + j * 1024);
        if ((q & 1) == 0)
          accE = __builtin_amdgcn_mfma_f32_32x32x16_bf16(bank[jb & 1][q], bfrag, accE, 0, 0, 0);
        else
          accO = __builtin_amdgcn_mfma_f32_32x32x16_bf16(bank[jb & 1][q], bfrag, accO, 0, 0, 0);
      }
      if (jb < 6) {
#pragma unroll
        for (int q = 0; q < 8; ++q)
          bank[jb & 1][q] = *(const short8*)(Asrc + (((jb + 2) * 8 + q) << 5));
      }
    }
#pragma unroll
    for (int r = 0; r < 16; ++r) accE[r] += accO[r];

    u16* Hn = (u16*)((char*)Hbuf + (long)(t + 1) * HSB);
    const int gate = ct * 2 + (col >> 4);
    const int hh   = col & 15;

    // two-phase gate bounce + fused cell epilogue
#pragma unroll
    for (int hp = 0; hp < 2; ++hp) {
      __syncthreads();
      if ((rt >> 1) == hp) {                   // rt 0,1 -> rows 0-63 ; rt 2,3 -> 64-127
#pragma unroll
        for (int r = 0; r < 16; ++r) {
          const int row64 = (rt & 1) * 32 + (r & 3) + 8 * (r >> 2) + 4 * hi;
          E[(row64 * 16 + hh) * 4 + gate] = accE[r];
        }
      }
      __syncthreads();
#pragma unroll
      for (int p = 0; p < 2; ++p) {
        const int r64 = rp * 2 + p;
        const float4 g4 = *(const float4*)&E[(r64 * 16 + hid) * 4];
        const float iv = sigm(g4.x + bi);
        const float fv = sigm(g4.y + bf_);
        const float gv = tanhx(g4.z + bg_);
        const float ov = sigm(g4.w + bo);
        const int ci = hp * 2 + p;
        const float cn = fv * creg[ci] + iv * gv;
        creg[ci] = cn;
        __hip_atomic_store(&Hn[(long)(m0 + hp * 64 + r64) * kH + ncol],
                           f2bf(ov * tanhx(cn)),
                           __ATOMIC_RELAXED, __HIP_MEMORY_SCOPE_AGENT);
      }
    }

    if (t < kT - 1) {
      __syncthreads();     // vmcnt(0) drain: all h stores device-visible
      if (tid == 0)        // own line: plain relaxed store, no RMW
        __hip_atomic_store(bar + myblk * 32, (u32)t,
                           __ATOMIC_RELAXED, __HIP_MEMORY_SCOPE_AGENT);
      if (tid < 64) {      // wave 0: lane l polls producer pblk's slot
        int guard = 0;
        while (__hip_atomic_load(bar + pblk * 32, __ATOMIC_RELAXED,
                                 __HIP_MEMORY_SCOPE_AGENT) < (u32)t) {
          __builtin_amdgcn_s_sleep(1);
          if (++guard > (1 << 20)) break;      // fail visibly, never hang
        }
      }
      __syncthreads();
    }
  }
}

// ---------------- prediction head ----------------
__global__ __launch_bounds__(256) void k_pred(
    const u16* __restrict__ Hbuf, long HS, int nsl,
    const u16* __restrict__ Wob, const float* __restrict__ b_out,
    float* __restrict__ out, int t0) {
  __shared__ u16 As[64 * 64];
  __shared__ u16 Bs[128 * 64];
  const int t = t0 + blockIdx.z;
  const u16* Hm = Hbuf + (long)((t + 1) % nsl) * HS;

  const int tid = threadIdx.x, lane = tid & 63, wid = tid >> 6;
  const int wr = wid >> 1, wc = wid & 1;
  const int m0 = blockIdx.y * 64;
  const int o0 = blockIdx.x * 128;
  const int hi = lane >> 4, l15 = lane & 15;

  floatx4 acc[2][4];
#pragma unroll
  for (int a2 = 0; a2 < 2; ++a2)
#pragma unroll
    for (int f = 0; f < 4; ++f)
#pragma unroll
      for (int r = 0; r < 4; ++r) acc[a2][f][r] = 0.0f;

  for (int kt = 0; kt < 16; ++kt) {
    const int kb = kt * 128;
#pragma unroll
    for (int i = 0; i < 2; ++i) {
      const int u = i * 256 + tid;
      const int row = u >> 3;
      const int off = (u & 7) * 16;
      const char* src = (const char*)Hm + ((long)(m0 + row) << 11) + kb +
                        (off ^ ((row & 7) << 4));
      gload16(src, (char*)As + (i * 256 + wid * 64) * 16);
    }
#pragma unroll
    for (int i = 0; i < 4; ++i) {
      const int u = i * 256 + tid;
      const int col = u >> 3;
      const int off = (u & 7) * 16;
      const char* src = (const char*)Wob + ((long)(o0 + col) << 11) + kb +
                        (off ^ ((col & 7) << 4));
      gload16(src, (char*)Bs + (i * 256 + wid * 64) * 16);
    }
    __syncthreads();
#pragma unroll
    for (int ks = 0; ks < 2; ++ks) {
      const int kbyte = ks * 64 + hi * 16;
      const int ra = wr * 32 + l15;
      short8 a0 = lds8((const char*)As + ra * 128 + (kbyte ^ ((ra & 7) << 4)));
      const int rb = ra + 16;
      short8 a1 = lds8((const char*)As + rb * 128 + (kbyte ^ ((rb & 7) << 4)));
#pragma unroll
      for (int f = 0; f < 4; ++f) {
        const int colx = wc * 64 + f * 16 + l15;
        short8 b = lds8((const char*)Bs + colx * 128 + (kbyte ^ ((colx & 7) << 4)));
        acc[0][f] = __builtin_amdgcn_mfma_f32_16x16x32_bf16(a0, b, acc[0][f], 0, 0, 0);
        acc[1][f] = __builtin_amdgcn_mfma_f32_16x16x32_bf16(a1, b, acc[1][f], 0, 0, 0);
      }
    }
    __syncthreads();
  }

#pragma unroll
  for (int f = 0; f < 4; ++f) {
    const int o = o0 + wc * 64 + f * 16 + l15;
    const float bb = b_out[o];
#pragma unroll
    for (int a2 = 0; a2 < 2; ++a2)
#pragma unroll
      for (int r = 0; r < 4; ++r) {
        const int row = m0 + wr * 32 + a2 * 16 + hi * 4 + r;
        out[((long)row * kT + t) * kO + o] = acc[a2][f][r] + bb;
      }
  }
}

// ---------------- launcher ----------------
extern "C" void kernel_launch(void* const* d_in, const int* in_sizes, int n_in,
                              void* d_out, int out_size, void* d_ws, size_t ws_size,
                              hipStream_t stream) {
  const float* enc  = (const float*)d_in[0];
  const float* Wih  = (const float*)d_in[2];
  const float* Whh  = (const float*)d_in[3];
  const float* bih  = (const float*)d_in[4];
  const float* bhh  = (const float*)d_in[5];
  const float* Wout = (const float*)d_in[6];
  const float* bout = (const float*)d_in[7];
  float* out = (float*)d_out;
  char*  ws  = (char*)d_ws;

  size_t off = 0;
  auto take = [&](size_t bytes) {
    size_t o = off; off += (bytes + 255) & ~(size_t)255; return o;
  };
  u16*   Wt0   = (u16*)(ws + take((size_t)kG * kH * 2));   // 8 MB
  u16*   Wt1   = (u16*)(ws + take((size_t)kG * kH * 2));   // 8 MB
  u16*   Wob   = (u16*)(ws + take((size_t)kO * kH * 2));   // 0.5 MB
  float* bias0 = (float*)(ws + take((size_t)kG * 4));
  float* bias1 = (float*)(ws + take((size_t)kG * 4));
  float* cst   = (float*)(ws + take((size_t)kB * kH * 4)); // 2 MB
  u32*   bar   = (u32*)(ws + take(256 * 128));             // 32 KB arrival slots
  const long HS = (long)kB * kH;
  u16* Hbuf = (u16*)(ws + off);
  const size_t havail = ws_size > off ? ws_size - off : 0;
  const bool fullhist = havail >= (size_t)(kT + 1) * HS * 2;
  const int nsl = fullhist ? (kT + 1) : 2;

  k_init<<<dim3(kB * kH / 256), dim3(256), 0, stream>>>(enc, cst, Hbuf);
  k_zbar<<<dim3(32), dim3(256), 0, stream>>>(bar);
  k_bias<<<dim3(kG / 256), dim3(256), 0, stream>>>(bih, bhh, Wih, bout, bias0, bias1);
  k_w0<<<dim3(kG), dim3(256), 0, stream>>>(Whh, Wt0);
  k_wo<<<dim3(kO * kH / 1024), dim3(256), 0, stream>>>(Wout, Wob);
  k_w1<<<dim3(256), dim3(256), 0, stream>>>(Wih, Wout, Whh, Wt1);

  if (fullhist) {
    k_step<<<dim3(kH / 32, kB / 64), dim3(256), 0, stream>>>(
        Hbuf, Hbuf + HS, cst, Wt0, bias0);
    k_persist<<<dim3(256), dim3(512), 0, stream>>>(Wt1, bias1, cst, Hbuf, bar);
    k_pred<<<dim3(kO / 128, kB / 64, kT), dim3(256), 0, stream>>>(
        Hbuf, HS, nsl, Wob, bout, out, 0);
  } else {
    for (int t = 0; t < kT; ++t) {
      const u16* Xp = Hbuf + (long)(t % nsl) * HS;
      u16*       Hn = Hbuf + (long)((t + 1) % nsl) * HS;
      k_step<<<dim3(kH / 32, kB / 64), dim3(256), 0, stream>>>(
          Xp, Hn, cst, t == 0 ? Wt0 : Wt1, t == 0 ? bias0 : bias1);
      k_pred<<<dim3(kO / 128, kB / 64, 1), dim3(256), 0, stream>>>(
          Hbuf, HS, nsl, Wob, bout, out, t);
    }
  }
}